// Round 12
// baseline (302.969 us; speedup 1.0000x reference)
//
#include <hip/hip_runtime.h>
#include <hip/hip_fp16.h>
#include <math.h>

#define N_NODES 50000
#define NPACK 25000                  // packed u16-pair words (full range)
#define E_EDGES 800000
#define NCHUNKS ((N_NODES + 1023) / 1024)
#define LIN_BLOCKS 1564              // 782 x-blocks * 2 (s/t)
#define QCH 64                       // histogram chunks per direction
#define CHUNK (E_EDGES / QCH)        // 12500 edges per chunk
#define CHUNK4 (CHUNK / 4)           // 3125 uint4 groups per chunk
#define OCT_NODES 12500              // node QUARTER per hist block
#define OCT_PACK 6250                // u32 words per quarter (25 KB LDS)
#define HIST_BLOCKS 512              // 4 quarters x 64 chunks x 2 dirs
#define HL_GRID (HIST_BLOCKS + LIN_BLOCKS)
#define FOCT_NODES 6250              // node half-quarter per fill block
#define FOCT_PACK 3125
#define FILL_BLOCKS 1024             // 8 foct x 64 chunks x 2 dirs
#define LCAP 4096                    // list slots per quarter-bucket (mean 3125, +20 sigma)

typedef _Float16 half8 __attribute__((ext_vector_type(8)));
typedef float f32x4 __attribute__((ext_vector_type(4)));

__device__ inline float fac_from(unsigned int u) {
    unsigned short us = (unsigned short)(u >> 16);
    __half h;
    __builtin_memcpy(&h, &us, 2);
    return __half2float(h);
}

// ====== once: convert lin2 (4x[32][64]) AND lin1 (4x[64][128]) weights to fp16 ======
__global__ __launch_bounds__(256) void w2h_kernel(const float* __restrict__ sW2a,
                                                  const float* __restrict__ sW2b,
                                                  const float* __restrict__ tW2a,
                                                  const float* __restrict__ tW2b,
                                                  const float* __restrict__ sW1a,
                                                  const float* __restrict__ sW1b,
                                                  const float* __restrict__ tW1a,
                                                  const float* __restrict__ tW1b,
                                                  __half* __restrict__ hw2,
                                                  __half* __restrict__ hw1) {
    int i = blockIdx.x * 256 + threadIdx.x;      // 0..40959
    if (i < 4 * 2048) {
        const float* s2[4] = { sW2a, sW2b, tW2a, tW2b };
        hw2[i] = __float2half(s2[i >> 11][i & 2047]);
        return;
    }
    int j = i - 4 * 2048;
    if (j < 4 * 8192) {
        const float* s1[4] = { sW1a, sW1b, tW1a, tW1b };
        hw1[j] = __float2half(s1[j >> 13][j & 8191]);
    }
}

// ===== FUSED: quarter-range LDS histogram + direct-slot edge lists + conv1 MFMA =====
__global__ __launch_bounds__(256) void hist_lin1_kernel(const int* __restrict__ ei0,
                                                        const int* __restrict__ ei1,
                                                        unsigned int* __restrict__ ghist,
                                                        unsigned short* __restrict__ list,
                                                        unsigned int* __restrict__ cnt_bkt,
                                                        const float* __restrict__ Xs,
                                                        const float* __restrict__ Xt,
                                                        const __half* __restrict__ hw1,
                                                        const float* __restrict__ sba,
                                                        const float* __restrict__ sbb,
                                                        const float* __restrict__ tba,
                                                        const float* __restrict__ tbb,
                                                        __half* __restrict__ As,
                                                        __half* __restrict__ At, int n) {
    __shared__ unsigned int h[OCT_PACK];     // 25 KB
    __shared__ unsigned int lcnt;
    int bx = blockIdx.x;
    int tid = threadIdx.x;
    if (bx < HIST_BLOCKS) {
        int oct = bx & 3, q = (bx >> 2) & 63, dir = bx >> 8;
        for (int i = tid; i < OCT_PACK; i += 256) h[i] = 0;
        if (tid == 0) lcnt = 0;
        __syncthreads();
        const int* key = dir ? ei0 : ei1;    // dir0: by target (fwd), dir1: by source (bwd)
        const uint4* key4 = (const uint4*)(key + q * CHUNK);
        unsigned short* lst = list + ((size_t)(dir * QCH + q) * 4 + oct) * LCAP;
        int lo = oct * OCT_NODES;
        for (int j = tid; j < CHUNK4; j += 256) {
            uint4 k4 = key4[j];
            int vv[4] = { (int)k4.x, (int)k4.y, (int)k4.z, (int)k4.w };
#pragma unroll
            for (int e = 0; e < 4; ++e) {
                unsigned int d = (unsigned int)(vv[e] - lo);
                if (d < OCT_NODES) {
                    atomicAdd(&h[d >> 1], 1u << ((d & 1) * 16));
                    unsigned int slot = atomicAdd(&lcnt, 1u);
                    if (slot < LCAP) lst[slot] = (unsigned short)(j * 4 + e);
                }
            }
        }
        __syncthreads();
        unsigned int* g = ghist + (size_t)(dir * QCH + q) * NPACK + oct * OCT_PACK;
        for (int i = tid; i < OCT_PACK; i += 256) g[i] = h[i];
        if (tid == 0) cnt_bkt[dir * 256 + q * 4 + oct] = (lcnt < LCAP) ? lcnt : LCAP;
        return;
    }
    // ---------------- lin1 MFMA role (fp16 weights; direct D-layout stores) ----------------
    int lidx = bx - HIST_BLOCKS;             // 0..1563
    int y = lidx & 1;
    int xb = lidx >> 1;                      // 0..781
    const float* X = y ? Xt : Xs;
    const __half* Wset[2] = { hw1 + (size_t)(y * 2 + 0) * 8192,
                              hw1 + (size_t)(y * 2 + 1) * 8192 };
    const float* bset[2] = { y ? tba : sba, y ? tbb : sbb };
    __half* A = y ? At : As;

    int w = tid >> 6, lane = tid & 63;
    int quad = lane >> 4, col = lane & 15;
    int node0 = xb * 64 + w * 16;

    half8 afrag[4];
    {
        int row = node0 + col;
        if (row >= n) row = n - 1;
        const float* xr = X + (size_t)row * 128 + quad * 8;
#pragma unroll
        for (int kc = 0; kc < 4; ++kc) {
            float4 f0 = *(const float4*)(xr + kc * 32);
            float4 f1 = *(const float4*)(xr + kc * 32 + 4);
            half8 hh;
            hh[0] = (_Float16)f0.x; hh[1] = (_Float16)f0.y;
            hh[2] = (_Float16)f0.z; hh[3] = (_Float16)f0.w;
            hh[4] = (_Float16)f1.x; hh[5] = (_Float16)f1.y;
            hh[6] = (_Float16)f1.z; hh[7] = (_Float16)f1.w;
            afrag[kc] = hh;
        }
    }

#pragma unroll
    for (int set = 0; set < 2; ++set) {
        const __half* Ws = Wset[set];
#pragma unroll
        for (int nt = 0; nt < 4; ++nt) {
            float bb = bset[set][nt * 16 + col];
            f32x4 acc = { bb, bb, bb, bb };
            const __half* wr = Ws + (size_t)(nt * 16 + col) * 128 + quad * 8;
#pragma unroll
            for (int kc = 0; kc < 4; ++kc) {
                half8 bfr = *(const half8*)(wr + kc * 32);
                acc = __builtin_amdgcn_mfma_f32_16x16x32_f16(afrag[kc], bfr, acc, 0, 0, 0);
            }
            // D: row = quad*4 + r, col = lane&15 -> direct fp16 store (unscaled)
#pragma unroll
            for (int r = 0; r < 4; ++r) {
                int node = node0 + quad * 4 + r;
                if (node < n)
                    A[(size_t)node * 128 + set * 64 + nt * 16 + col] = __float2half(acc[r]);
            }
        }
    }
}

// ====== FUSED scan: per-column nodescan walk + degree factors + block node-scan ======
// grid (NCHUNKS, 2) x 1024 threads. Phase A (512 threads): walk 64 chunk slices of
// this block's 512 packed columns, leave exclusive chunk-bases in ghist, compute
// degree factors (dsi/dti + half tables) inline. Phase B: 1024-wide block scan.
// Replaces nodescan + scan_chunk2 + addback's factor work; cntp eliminated.
__global__ __launch_bounds__(1024) void scan_fused_kernel(unsigned int* __restrict__ ghist,
                                                          int* __restrict__ offs_f,
                                                          int* __restrict__ offs_b,
                                                          int* __restrict__ part_f,
                                                          int* __restrict__ part_b,
                                                          float* __restrict__ dsi,
                                                          float* __restrict__ dti,
                                                          unsigned short* __restrict__ h_dsi,
                                                          unsigned short* __restrict__ h_dti,
                                                          int n) {
    __shared__ int sh[1024];
    int dir = blockIdx.y;
    int bx = blockIdx.x;
    int tid = threadIdx.x;
    if (tid < 512) {
        int vp = bx * 512 + tid;
        unsigned int lo = 0, hi = 0;
        if (vp < NPACK) {
            unsigned int* g = ghist + (size_t)dir * QCH * NPACK + vp;
#pragma unroll 4
            for (int q = 0; q < QCH; ++q) {
                unsigned int w = g[(size_t)q * NPACK];
                g[(size_t)q * NPACK] = lo | (hi << 16);
                lo += w & 0xffff;
                hi += w >> 16;
            }
            float f0 = rsqrtf((float)(lo + 1));
            float f1 = rsqrtf((float)(hi + 1));
            __half hf0 = __float2half(f0), hf1 = __float2half(f1);
            unsigned short hb0, hb1;
            __builtin_memcpy(&hb0, &hf0, 2);
            __builtin_memcpy(&hb1, &hf1, 2);
            int v0 = vp * 2, v1 = vp * 2 + 1;
            if (dir == 0) {                  // fwd: in-degrees -> dti
                dti[v0] = f0; dti[v1] = f1;
                h_dti[v0] = hb0; h_dti[v1] = hb1;
            } else {                         // bwd: out-degrees -> dsi
                dsi[v0] = f0; dsi[v1] = f1;
                h_dsi[v0] = hb0; h_dsi[v1] = hb1;
            }
        }
        sh[2 * tid]     = (int)lo;
        sh[2 * tid + 1] = (int)hi;
    }
    __syncthreads();
    int i = bx * 1024 + tid;
    int v = sh[tid];
    __syncthreads();
    // 1024-wide inclusive block scan (as before)
    int run = v;
    sh[tid] = run;
    __syncthreads();
    for (int off = 1; off < 1024; off <<= 1) {
        int add = (tid >= off) ? sh[tid - off] : 0;
        __syncthreads();
        sh[tid] += add;
        __syncthreads();
    }
    int* offs = dir ? offs_b : offs_f;
    int* partials = dir ? part_b : part_f;
    if (i < n) offs[i] = sh[tid] - v;
    if (tid == 1023) partials[bx] = sh[tid];
}

// slim addback: inline partials scan + offs add only
__global__ __launch_bounds__(256) void addback_kernel(int* __restrict__ offs_f,
                                                      int* __restrict__ offs_b,
                                                      const int* __restrict__ part_f,
                                                      const int* __restrict__ part_b,
                                                      int n, int nchunks) {
    __shared__ int sp[64];
    int tid = threadIdx.x;
    const int* part = blockIdx.y ? part_b : part_f;
    int* offs = blockIdx.y ? offs_b : offs_f;
    if (tid < 64) sp[tid] = (tid < nchunks) ? part[tid] : 0;
    __syncthreads();
    if (tid == 0) {                       // tiny serial exclusive scan (49 entries)
        int run = 0;
        for (int k = 0; k < 64; ++k) { int t = sp[k]; sp[k] = run; run += t; }
    }
    __syncthreads();
    int i = blockIdx.x * 256 + tid;
    if (i < n) offs[i] += sp[i >> 10];
    else if (i == n) offs[n] = sp[nchunks];
}

// ============ fill: list-driven scatter; pos-base LDS atomic gives pay slot ============
__global__ __launch_bounds__(256) void fill_kernel(const int* __restrict__ ei0,
                                                   const int* __restrict__ ei1,
                                                   const unsigned int* __restrict__ ghist,
                                                   const int* __restrict__ offs_f,
                                                   const int* __restrict__ offs_b,
                                                   const unsigned short* __restrict__ h_dsi,
                                                   const unsigned short* __restrict__ h_dti,
                                                   unsigned int* __restrict__ pay_f,
                                                   unsigned int* __restrict__ pay_b,
                                                   const unsigned short* __restrict__ list,
                                                   const unsigned int* __restrict__ cnt_bkt) {
    __shared__ unsigned int pos[FOCT_NODES]; // 25 KB: per-node NEXT global pay slot
    int bx = blockIdx.x;
    int foct = bx & 7, q = (bx >> 3) & 63, dir = bx >> 9;
    int oct = foct >> 1;                     // parent quarter
    int tid = threadIdx.x;
    const unsigned int* pref = ghist + (size_t)(dir * QCH + q) * NPACK + foct * FOCT_PACK;
    const int* offs = dir ? offs_b : offs_f;
    int lo = foct * FOCT_NODES;
    for (int d = tid; d < FOCT_NODES; d += 256) {
        unsigned int pw = pref[d >> 1];
        int cb = (d & 1) ? (int)(pw >> 16) : (int)(pw & 0xffff);
        pos[d] = (unsigned int)(offs[lo + d] + cb);
    }
    __syncthreads();
    const int* key = dir ? ei0 : ei1;
    const int* pid = dir ? ei1 : ei0;
    const unsigned short* hfac = dir ? h_dti : h_dsi;
    unsigned int* pay = dir ? pay_b : pay_f;
    const unsigned short* lst = list + ((size_t)(dir * QCH + q) * 4 + oct) * LCAP;
    int cnt = (int)cnt_bkt[dir * 256 + q * 4 + oct];
    int base = q * CHUNK;
    for (int j = tid; j < cnt; j += 256) {
        int gi = base + (int)lst[j];
        int v = key[gi];
        unsigned int d = (unsigned int)(v - lo);
        if (d < FOCT_NODES) {
            int id = pid[gi];
            unsigned int p = atomicAdd(&pos[d], 1u);
            unsigned int hb = hfac[id];
            pay[p] = (unsigned int)id | (hb << 16);
        }
    }
}

__device__ inline void acc_fma(float* acc, uint4 u, float f) {
    const __half2* h = (const __half2*)&u;
    float2 f0 = __half22float2(h[0]);
    float2 f1 = __half22float2(h[1]);
    float2 f2 = __half22float2(h[2]);
    float2 f3 = __half22float2(h[3]);
    acc[0] += f * f0.x; acc[1] += f * f0.y; acc[2] += f * f1.x; acc[3] += f * f1.y;
    acc[4] += f * f2.x; acc[5] += f * f2.y; acc[6] += f * f3.x; acc[7] += f * f3.y;
}

// ======= conv1-aggregate + relu + conv2 via MFMA epilogue; s/t via blockIdx.y =======
// 8-deep gather unroll (r12): doubles per-thread outstanding row loads (MLP 4->8).
__global__ __launch_bounds__(256) void pull_lin2_kernel(const __half* __restrict__ As,
                                                        const __half* __restrict__ At,
                                                        __half* __restrict__ Cs,
                                                        __half* __restrict__ Ct,
                                                        const int* __restrict__ offs_f,
                                                        const int* __restrict__ offs_b,
                                                        const unsigned int* __restrict__ pay_f,
                                                        const unsigned int* __restrict__ pay_b,
                                                        const float* __restrict__ dsi,
                                                        const float* __restrict__ dti,
                                                        const float* __restrict__ sb2a,
                                                        const float* __restrict__ sb2b,
                                                        const float* __restrict__ tb2a,
                                                        const float* __restrict__ tb2b,
                                                        const __half* __restrict__ hw2, int n) {
    int y = blockIdx.y;
    const __half* xw = y ? At : As;
    __half* C = y ? Ct : Cs;
    const int* offs = y ? offs_b : offs_f;
    const unsigned int* pay = y ? pay_b : pay_f;
    const float* fac_self  = y ? dsi : dti;   // fwd: dti, bwd: dsi
    const float* fac_other = y ? dti : dsi;   // self-loop gather factor
    const float* b2a = y ? tb2a : sb2a;
    const float* b2b = y ? tb2b : sb2b;

    __shared__ __half xsh[16 * 136];          // 4.25 KB; row pad -> 2-way-free banks

    int tid = threadIdx.x;
    int ln = tid >> 4;     // node slot 0..15
    int f4 = tid & 15;     // uint4 column (8 halves)
    int v = blockIdx.x * 16 + ln;
    int i = offs[v], end = offs[v + 1];
    const uint4* xw16 = (const uint4*)xw;           // row stride = 16 uint4

    float acc[8] = {0, 0, 0, 0, 0, 0, 0, 0};
    acc_fma(acc, xw16[v * 16 + f4], fac_other[v]);  // self-loop
    while (i < end && (i & 3)) {                    // align to 16B pay boundary
        unsigned int pk = pay[i];
        acc_fma(acc, xw16[(pk & 0xffff) * 16 + f4], fac_from(pk));
        ++i;
    }
    for (; i + 7 < end; i += 8) {                   // 2 uint4 pay loads + 8 gathers in flight
        uint4 pk0 = *(const uint4*)(pay + i);
        uint4 pk1 = *(const uint4*)(pay + i + 4);
        uint4 ua = xw16[(pk0.x & 0xffff) * 16 + f4];
        uint4 ub = xw16[(pk0.y & 0xffff) * 16 + f4];
        uint4 uc = xw16[(pk0.z & 0xffff) * 16 + f4];
        uint4 ud = xw16[(pk0.w & 0xffff) * 16 + f4];
        uint4 ue = xw16[(pk1.x & 0xffff) * 16 + f4];
        uint4 uf = xw16[(pk1.y & 0xffff) * 16 + f4];
        uint4 ug = xw16[(pk1.z & 0xffff) * 16 + f4];
        uint4 uh = xw16[(pk1.w & 0xffff) * 16 + f4];
        acc_fma(acc, ua, fac_from(pk0.x));
        acc_fma(acc, ub, fac_from(pk0.y));
        acc_fma(acc, uc, fac_from(pk0.z));
        acc_fma(acc, ud, fac_from(pk0.w));
        acc_fma(acc, ue, fac_from(pk1.x));
        acc_fma(acc, uf, fac_from(pk1.y));
        acc_fma(acc, ug, fac_from(pk1.z));
        acc_fma(acc, uh, fac_from(pk1.w));
    }
    for (; i + 3 < end; i += 4) {
        uint4 pk = *(const uint4*)(pay + i);
        uint4 ua = xw16[(pk.x & 0xffff) * 16 + f4];
        uint4 ub = xw16[(pk.y & 0xffff) * 16 + f4];
        uint4 uc = xw16[(pk.z & 0xffff) * 16 + f4];
        uint4 ud = xw16[(pk.w & 0xffff) * 16 + f4];
        acc_fma(acc, ua, fac_from(pk.x));
        acc_fma(acc, ub, fac_from(pk.y));
        acc_fma(acc, uc, fac_from(pk.z));
        acc_fma(acc, ud, fac_from(pk.w));
    }
    for (; i < end; ++i) {
        unsigned int pk = pay[i];
        acc_fma(acc, xw16[(pk & 0xffff) * 16 + f4], fac_from(pk));
    }

    float fs = fac_self[v];
    half8 hx;
#pragma unroll
    for (int j = 0; j < 8; ++j) hx[j] = (_Float16)fmaxf(acc[j] * fs, 0.0f);
    *(half8*)&xsh[ln * 136 + f4 * 8] = hx;
    __syncthreads();

    // ---- MFMA epilogue: wave w -> set s = w>>1 (a:mu / b:logstd), n-tile nt = w&1 ----
    int w = tid >> 6, lane = tid & 63;
    int s = w >> 1, nt = w & 1;
    int quad = lane >> 4, col = lane & 15;
    float bb = (s ? b2b : b2a)[nt * 16 + col];
    f32x4 cacc = { bb, bb, bb, bb };
    const __half* hw = hw2 + (size_t)(y * 2 + s) * 2048;   // [32][64] fp16 row-major
#pragma unroll
    for (int t = 0; t < 2; ++t) {
        half8 af = *(const half8*)&xsh[col * 136 + s * 64 + t * 32 + quad * 8];
        half8 bf = *(const half8*)&hw[(nt * 16 + col) * 64 + t * 32 + quad * 8];
        cacc = __builtin_amdgcn_mfma_f32_16x16x32_f16(af, bf, cacc, 0, 0, 0);
    }
    // D: row m = quad*4 + r (node), col n = lane&15; C stored UNSCALED fp16
    int vbase = blockIdx.x * 16 + quad * 4;
    int o = s * 32 + nt * 16 + col;
#pragma unroll
    for (int r = 0; r < 4; ++r)
        C[(size_t)(vbase + r) * 64 + o] = __float2half(cacc[r]);
}

// ================= final pull + reparametrize; s/t via blockIdx.y =================
__global__ __launch_bounds__(256) void final_pull2_kernel(const __half* __restrict__ Cs,
                                                          const __half* __restrict__ Ct,
                                                          float* __restrict__ out_s,
                                                          float* __restrict__ out_t,
                                                          const int* __restrict__ offs_f,
                                                          const int* __restrict__ offs_b,
                                                          const unsigned int* __restrict__ pay_f,
                                                          const unsigned int* __restrict__ pay_b,
                                                          const float* __restrict__ dsi,
                                                          const float* __restrict__ dti,
                                                          const float* __restrict__ noise_s,
                                                          const float* __restrict__ noise_t,
                                                          int n) {
    int y = blockIdx.y;
    const __half* xw = y ? Ct : Cs;
    float* out = y ? out_t : out_s;
    const int* offs = y ? offs_f : offs_b;                  // flipped vs conv1
    const unsigned int* pay = y ? pay_f : pay_b;
    const float* fac_self  = y ? dti : dsi;
    const float* fac_other = y ? dsi : dti;                 // self-loop gather factor
    const float* noise = y ? noise_t : noise_s;

    const uint4* xw16 = (const uint4*)xw;           // row stride = 8 uint4 (64 halves)
    int ln = threadIdx.x >> 3;
    int f4 = threadIdx.x & 7;
    int v = blockIdx.x * 32 + ln;
    if (v >= n) return;
    int i = offs[v], end = offs[v + 1];

    float acc[8] = {0, 0, 0, 0, 0, 0, 0, 0};
    acc_fma(acc, xw16[v * 8 + f4], fac_other[v]);
    while (i < end && (i & 3)) {
        unsigned int pk = pay[i];
        acc_fma(acc, xw16[(pk & 0xffff) * 8 + f4], fac_from(pk));
        ++i;
    }
    for (; i + 7 < end; i += 8) {                   // 8-deep gather unroll
        uint4 pk0 = *(const uint4*)(pay + i);
        uint4 pk1 = *(const uint4*)(pay + i + 4);
        uint4 ua = xw16[(pk0.x & 0xffff) * 8 + f4];
        uint4 ub = xw16[(pk0.y & 0xffff) * 8 + f4];
        uint4 uc = xw16[(pk0.z & 0xffff) * 8 + f4];
        uint4 ud = xw16[(pk0.w & 0xffff) * 8 + f4];
        uint4 ue = xw16[(pk1.x & 0xffff) * 8 + f4];
        uint4 uf = xw16[(pk1.y & 0xffff) * 8 + f4];
        uint4 ug = xw16[(pk1.z & 0xffff) * 8 + f4];
        uint4 uh = xw16[(pk1.w & 0xffff) * 8 + f4];
        acc_fma(acc, ua, fac_from(pk0.x));
        acc_fma(acc, ub, fac_from(pk0.y));
        acc_fma(acc, uc, fac_from(pk0.z));
        acc_fma(acc, ud, fac_from(pk0.w));
        acc_fma(acc, ue, fac_from(pk1.x));
        acc_fma(acc, uf, fac_from(pk1.y));
        acc_fma(acc, ug, fac_from(pk1.z));
        acc_fma(acc, uh, fac_from(pk1.w));
    }
    for (; i + 3 < end; i += 4) {
        uint4 pk = *(const uint4*)(pay + i);
        uint4 ua = xw16[(pk.x & 0xffff) * 8 + f4];
        uint4 ub = xw16[(pk.y & 0xffff) * 8 + f4];
        uint4 uc = xw16[(pk.z & 0xffff) * 8 + f4];
        uint4 ud = xw16[(pk.w & 0xffff) * 8 + f4];
        acc_fma(acc, ua, fac_from(pk.x));
        acc_fma(acc, ub, fac_from(pk.y));
        acc_fma(acc, uc, fac_from(pk.z));
        acc_fma(acc, ud, fac_from(pk.w));
    }
    for (; i < end; ++i) {
        unsigned int pk = pay[i];
        acc_fma(acc, xw16[(pk & 0xffff) * 8 + f4], fac_from(pk));
    }

    float fs = fac_self[v];
#pragma unroll
    for (int j = 0; j < 8; ++j) acc[j] *= fs;

    // lanes f4 0..3 hold mu cols; partner lane f4+4 holds logstd cols
    int lane = threadIdx.x & 63;
    float lg[8];
#pragma unroll
    for (int j = 0; j < 8; ++j) lg[j] = __shfl(acc[j], lane + 4);
    if (f4 < 4) {
        const float4* nz4 = (const float4*)noise;
        float4 n0 = nz4[v * 8 + f4 * 2];
        float4 n1 = nz4[v * 8 + f4 * 2 + 1];
        float4 r0, r1;
        r0.x = acc[0] + n0.x * expf(lg[0]) * 0.2f;
        r0.y = acc[1] + n0.y * expf(lg[1]) * 0.2f;
        r0.z = acc[2] + n0.z * expf(lg[2]) * 0.2f;
        r0.w = acc[3] + n0.w * expf(lg[3]) * 0.2f;
        r1.x = acc[4] + n1.x * expf(lg[4]) * 0.2f;
        r1.y = acc[5] + n1.y * expf(lg[5]) * 0.2f;
        r1.z = acc[6] + n1.z * expf(lg[6]) * 0.2f;
        r1.w = acc[7] + n1.w * expf(lg[7]) * 0.2f;
        float4* o4 = (float4*)out;
        o4[v * 8 + f4 * 2]     = r0;
        o4[v * 8 + f4 * 2 + 1] = r1;
    }
}

// ================= driver =================
extern "C" void kernel_launch(void* const* d_in, const int* in_sizes, int n_in,
                              void* d_out, int out_size, void* d_ws, size_t ws_size,
                              hipStream_t stream) {
    const float* s       = (const float*)d_in[0];
    const float* t       = (const float*)d_in[1];
    const int*   ei      = (const int*)d_in[2];
    const float* noise_s = (const float*)d_in[3];
    const float* noise_t = (const float*)d_in[4];
    const float* sm1_W = (const float*)d_in[5];  const float* sm1_b = (const float*)d_in[6];
    const float* sm2_W = (const float*)d_in[7];  const float* sm2_b = (const float*)d_in[8];
    const float* sl1_W = (const float*)d_in[9];  const float* sl1_b = (const float*)d_in[10];
    const float* sl2_W = (const float*)d_in[11]; const float* sl2_b = (const float*)d_in[12];
    const float* tm1_W = (const float*)d_in[13]; const float* tm1_b = (const float*)d_in[14];
    const float* tm2_W = (const float*)d_in[15]; const float* tm2_b = (const float*)d_in[16];
    const float* tl1_W = (const float*)d_in[17]; const float* tl1_b = (const float*)d_in[18];
    const float* tl2_W = (const float*)d_in[19]; const float* tl2_b = (const float*)d_in[20];

    const int* ei0 = ei;            // sources
    const int* ei1 = ei + E_EDGES;  // targets

    __half* A_s = (__half*)d_ws;                       // [N][128] unscaled fp16
    __half* A_t = A_s + (size_t)N_NODES * 128;         // [N][128]
    __half* C_s = A_t + (size_t)N_NODES * 128;         // [N][64] unscaled fp16
    __half* C_t = C_s + (size_t)N_NODES * 64;          // [N][64]
    unsigned int* pay_fwd = (unsigned int*)(C_t + (size_t)N_NODES * 64);  // E (16B-aligned)
    unsigned int* pay_bwd = pay_fwd + E_EDGES;                            // E
    float* dsi = (float*)(pay_bwd + E_EDGES);          // N
    float* dti = dsi + N_NODES;                        // N
    int* offs_fwd = (int*)(dti + N_NODES);             // N+1
    int* offs_bwd = offs_fwd + N_NODES + 1;            // N+1
    int* part_fwd = offs_bwd + N_NODES + 1;            // NCHUNKS+1
    int* part_bwd = part_fwd + NCHUNKS + 1;            // NCHUNKS+1
    unsigned short* h_dsi = (unsigned short*)(part_bwd + NCHUNKS + 1);  // N half factors
    unsigned short* h_dti = h_dsi + N_NODES;           // N half factors
    unsigned short* list  = h_dti + N_NODES;           // [512][LCAP] u16 = 4 MB
    unsigned int* cnt_bkt = (unsigned int*)(list + (size_t)HIST_BLOCKS * LCAP);  // 512 u32
    __half* hw2 = (__half*)(((uintptr_t)(cnt_bkt + 512) + 15) & ~(uintptr_t)15);  // [4][2048] fp16
    __half* hw1 = hw2 + 4 * 2048;                      // [4][8192] fp16 (lin1 weights)
    // total ~50 MB

    // ghist ALIASES the C region (both exactly 12.8 MB):
    // ghist live hist->fill; C written by pull_lin2 (after fill), read by final_pull2.
    unsigned int* ghist = (unsigned int*)C_s;          // [2][QCH][NPACK]

    float* s_out = (float*)d_out;
    float* t_out = (float*)d_out + N_NODES * 32;

    dim3 blk(256);
    dim3 agrid((N_NODES + 1 + 255) / 256, 2);
    dim3 pgrid(N_NODES / 16, 2);           // 3125 x 2
    dim3 fgrid((N_NODES + 31) / 32, 2);    // 1563 x 2

    // ---- fp16 weights for lin2 AND lin1 (one tiny launch; runs before hist_lin1) ----
    w2h_kernel<<<160, blk, 0, stream>>>(sm2_W, sl2_W, tm2_W, tl2_W,
                                        sm1_W, sl1_W, tm1_W, tl1_W, hw2, hw1);
    // ---- hist (+edge lists) fused with conv1 dual-linear (overlap) ----
    hist_lin1_kernel<<<HL_GRID, blk, 0, stream>>>(
        ei0, ei1, ghist, list, cnt_bkt,
        s, t, hw1, sm1_b, sl1_b, tm1_b, tl1_b,
        A_s, A_t, N_NODES);
    // ---- fused nodescan + block scan + degree factors ----
    scan_fused_kernel<<<dim3(NCHUNKS, 2), 1024, 0, stream>>>(
        ghist, offs_fwd, offs_bwd, part_fwd, part_bwd,
        dsi, dti, h_dsi, h_dti, N_NODES);
    addback_kernel<<<agrid, blk, 0, stream>>>(offs_fwd, offs_bwd, part_fwd, part_bwd,
                                              N_NODES, NCHUNKS);
    // ---- list-driven fill (half-quarter blocks; pos-base LDS atomics) ----
    fill_kernel<<<FILL_BLOCKS, blk, 0, stream>>>(ei0, ei1, ghist, offs_fwd, offs_bwd,
                                                 h_dsi, h_dti, pay_fwd, pay_bwd,
                                                 list, cnt_bkt);

    // ---- pulls (packed-factor gathers; MFMA lin2 epilogue) ----
    pull_lin2_kernel<<<pgrid, blk, 0, stream>>>(A_s, A_t, C_s, C_t,
                                                offs_fwd, offs_bwd, pay_fwd, pay_bwd,
                                                dsi, dti,
                                                sm2_b, sl2_b, tm2_b, tl2_b, hw2, N_NODES);
    final_pull2_kernel<<<fgrid, blk, 0, stream>>>(C_s, C_t, s_out, t_out,
                                                  offs_fwd, offs_bwd, pay_fwd, pay_bwd,
                                                  dsi, dti, noise_s, noise_t, N_NODES);
}

// Round 13
// 298.021 us; speedup vs baseline: 1.0166x; 1.0166x over previous
//
#include <hip/hip_runtime.h>
#include <hip/hip_fp16.h>
#include <math.h>

#define N_NODES 50000
#define NPACK 25000                  // packed u16-pair words (full range)
#define E_EDGES 800000
#define NCHUNKS ((N_NODES + 1023) / 1024)
#define LIN_BLOCKS 1564              // 782 x-blocks * 2 (s/t)
#define QCH 64                       // histogram chunks per direction
#define CHUNK (E_EDGES / QCH)        // 12500 edges per chunk
#define CHUNK4 (CHUNK / 4)           // 3125 uint4 groups per chunk
#define OCT_NODES 12500              // node QUARTER per hist block
#define OCT_PACK 6250                // u32 words per quarter (25 KB LDS)
#define HIST_BLOCKS 512              // 4 quarters x 64 chunks x 2 dirs
#define HL_GRID (HIST_BLOCKS + LIN_BLOCKS)
#define FOCT_NODES 6250              // node half-quarter per fill block
#define FOCT_PACK 3125
#define FILL_BLOCKS 1024             // 8 foct x 64 chunks x 2 dirs
#define LCAP 4096                    // list slots per quarter-bucket (mean 3125, +20 sigma)

typedef _Float16 half8 __attribute__((ext_vector_type(8)));
typedef float f32x4 __attribute__((ext_vector_type(4)));

__device__ inline float fac_from(unsigned int u) {
    unsigned short us = (unsigned short)(u >> 16);
    __half h;
    __builtin_memcpy(&h, &us, 2);
    return __half2float(h);
}

// ====== once: convert lin2 (4x[32][64]) AND lin1 (4x[64][128]) weights to fp16 ======
__global__ __launch_bounds__(256) void w2h_kernel(const float* __restrict__ sW2a,
                                                  const float* __restrict__ sW2b,
                                                  const float* __restrict__ tW2a,
                                                  const float* __restrict__ tW2b,
                                                  const float* __restrict__ sW1a,
                                                  const float* __restrict__ sW1b,
                                                  const float* __restrict__ tW1a,
                                                  const float* __restrict__ tW1b,
                                                  __half* __restrict__ hw2,
                                                  __half* __restrict__ hw1) {
    int i = blockIdx.x * 256 + threadIdx.x;      // 0..40959
    if (i < 4 * 2048) {
        const float* s2[4] = { sW2a, sW2b, tW2a, tW2b };
        hw2[i] = __float2half(s2[i >> 11][i & 2047]);
        return;
    }
    int j = i - 4 * 2048;
    if (j < 4 * 8192) {
        const float* s1[4] = { sW1a, sW1b, tW1a, tW1b };
        hw1[j] = __float2half(s1[j >> 13][j & 8191]);
    }
}

// ===== FUSED: quarter-range LDS histogram + direct-slot edge lists + conv1 MFMA =====
__global__ __launch_bounds__(256) void hist_lin1_kernel(const int* __restrict__ ei0,
                                                        const int* __restrict__ ei1,
                                                        unsigned int* __restrict__ ghist,
                                                        unsigned short* __restrict__ list,
                                                        unsigned int* __restrict__ cnt_bkt,
                                                        const float* __restrict__ Xs,
                                                        const float* __restrict__ Xt,
                                                        const __half* __restrict__ hw1,
                                                        const float* __restrict__ sba,
                                                        const float* __restrict__ sbb,
                                                        const float* __restrict__ tba,
                                                        const float* __restrict__ tbb,
                                                        __half* __restrict__ As,
                                                        __half* __restrict__ At, int n) {
    __shared__ unsigned int h[OCT_PACK];     // 25 KB
    __shared__ unsigned int lcnt;
    int bx = blockIdx.x;
    int tid = threadIdx.x;
    if (bx < HIST_BLOCKS) {
        int oct = bx & 3, q = (bx >> 2) & 63, dir = bx >> 8;
        for (int i = tid; i < OCT_PACK; i += 256) h[i] = 0;
        if (tid == 0) lcnt = 0;
        __syncthreads();
        const int* key = dir ? ei0 : ei1;    // dir0: by target (fwd), dir1: by source (bwd)
        const uint4* key4 = (const uint4*)(key + q * CHUNK);
        unsigned short* lst = list + ((size_t)(dir * QCH + q) * 4 + oct) * LCAP;
        int lo = oct * OCT_NODES;
        for (int j = tid; j < CHUNK4; j += 256) {
            uint4 k4 = key4[j];
            int vv[4] = { (int)k4.x, (int)k4.y, (int)k4.z, (int)k4.w };
#pragma unroll
            for (int e = 0; e < 4; ++e) {
                unsigned int d = (unsigned int)(vv[e] - lo);
                if (d < OCT_NODES) {
                    atomicAdd(&h[d >> 1], 1u << ((d & 1) * 16));
                    unsigned int slot = atomicAdd(&lcnt, 1u);
                    if (slot < LCAP) lst[slot] = (unsigned short)(j * 4 + e);
                }
            }
        }
        __syncthreads();
        unsigned int* g = ghist + (size_t)(dir * QCH + q) * NPACK + oct * OCT_PACK;
        for (int i = tid; i < OCT_PACK; i += 256) g[i] = h[i];
        if (tid == 0) cnt_bkt[dir * 256 + q * 4 + oct] = (lcnt < LCAP) ? lcnt : LCAP;
        return;
    }
    // ---------------- lin1 MFMA role (fp16 weights; direct D-layout stores) ----------------
    int lidx = bx - HIST_BLOCKS;             // 0..1563
    int y = lidx & 1;
    int xb = lidx >> 1;                      // 0..781
    const float* X = y ? Xt : Xs;
    const __half* Wset[2] = { hw1 + (size_t)(y * 2 + 0) * 8192,
                              hw1 + (size_t)(y * 2 + 1) * 8192 };
    const float* bset[2] = { y ? tba : sba, y ? tbb : sbb };
    __half* A = y ? At : As;

    int w = tid >> 6, lane = tid & 63;
    int quad = lane >> 4, col = lane & 15;
    int node0 = xb * 64 + w * 16;

    half8 afrag[4];
    {
        int row = node0 + col;
        if (row >= n) row = n - 1;
        const float* xr = X + (size_t)row * 128 + quad * 8;
#pragma unroll
        for (int kc = 0; kc < 4; ++kc) {
            float4 f0 = *(const float4*)(xr + kc * 32);
            float4 f1 = *(const float4*)(xr + kc * 32 + 4);
            half8 hh;
            hh[0] = (_Float16)f0.x; hh[1] = (_Float16)f0.y;
            hh[2] = (_Float16)f0.z; hh[3] = (_Float16)f0.w;
            hh[4] = (_Float16)f1.x; hh[5] = (_Float16)f1.y;
            hh[6] = (_Float16)f1.z; hh[7] = (_Float16)f1.w;
            afrag[kc] = hh;
        }
    }

#pragma unroll
    for (int set = 0; set < 2; ++set) {
        const __half* Ws = Wset[set];
#pragma unroll
        for (int nt = 0; nt < 4; ++nt) {
            float bb = bset[set][nt * 16 + col];
            f32x4 acc = { bb, bb, bb, bb };
            const __half* wr = Ws + (size_t)(nt * 16 + col) * 128 + quad * 8;
#pragma unroll
            for (int kc = 0; kc < 4; ++kc) {
                half8 bfr = *(const half8*)(wr + kc * 32);
                acc = __builtin_amdgcn_mfma_f32_16x16x32_f16(afrag[kc], bfr, acc, 0, 0, 0);
            }
            // D: row = quad*4 + r, col = lane&15 -> direct fp16 store (unscaled)
#pragma unroll
            for (int r = 0; r < 4; ++r) {
                int node = node0 + quad * 4 + r;
                if (node < n)
                    A[(size_t)node * 128 + set * 64 + nt * 16 + col] = __float2half(acc[r]);
            }
        }
    }
}

// ====== FUSED scan: per-column nodescan walk + degree factors + block node-scan ======
__global__ __launch_bounds__(1024) void scan_fused_kernel(unsigned int* __restrict__ ghist,
                                                          int* __restrict__ offs_f,
                                                          int* __restrict__ offs_b,
                                                          int* __restrict__ part_f,
                                                          int* __restrict__ part_b,
                                                          float* __restrict__ dsi,
                                                          float* __restrict__ dti,
                                                          unsigned short* __restrict__ h_dsi,
                                                          unsigned short* __restrict__ h_dti,
                                                          int n) {
    __shared__ int sh[1024];
    int dir = blockIdx.y;
    int bx = blockIdx.x;
    int tid = threadIdx.x;
    if (tid < 512) {
        int vp = bx * 512 + tid;
        unsigned int lo = 0, hi = 0;
        if (vp < NPACK) {
            unsigned int* g = ghist + (size_t)dir * QCH * NPACK + vp;
#pragma unroll 4
            for (int q = 0; q < QCH; ++q) {
                unsigned int w = g[(size_t)q * NPACK];
                g[(size_t)q * NPACK] = lo | (hi << 16);
                lo += w & 0xffff;
                hi += w >> 16;
            }
            float f0 = rsqrtf((float)(lo + 1));
            float f1 = rsqrtf((float)(hi + 1));
            __half hf0 = __float2half(f0), hf1 = __float2half(f1);
            unsigned short hb0, hb1;
            __builtin_memcpy(&hb0, &hf0, 2);
            __builtin_memcpy(&hb1, &hf1, 2);
            int v0 = vp * 2, v1 = vp * 2 + 1;
            if (dir == 0) {                  // fwd: in-degrees -> dti
                dti[v0] = f0; dti[v1] = f1;
                h_dti[v0] = hb0; h_dti[v1] = hb1;
            } else {                         // bwd: out-degrees -> dsi
                dsi[v0] = f0; dsi[v1] = f1;
                h_dsi[v0] = hb0; h_dsi[v1] = hb1;
            }
        }
        sh[2 * tid]     = (int)lo;
        sh[2 * tid + 1] = (int)hi;
    }
    __syncthreads();
    int i = bx * 1024 + tid;
    int v = sh[tid];
    __syncthreads();
    // 1024-wide inclusive block scan
    sh[tid] = v;
    __syncthreads();
    for (int off = 1; off < 1024; off <<= 1) {
        int add = (tid >= off) ? sh[tid - off] : 0;
        __syncthreads();
        sh[tid] += add;
        __syncthreads();
    }
    int* offs = dir ? offs_b : offs_f;
    int* partials = dir ? part_b : part_f;
    if (i < n) offs[i] = sh[tid] - v;
    if (tid == 1023) partials[bx] = sh[tid];
}

// slim addback: inline partials scan + offs add only
__global__ __launch_bounds__(256) void addback_kernel(int* __restrict__ offs_f,
                                                      int* __restrict__ offs_b,
                                                      const int* __restrict__ part_f,
                                                      const int* __restrict__ part_b,
                                                      int n, int nchunks) {
    __shared__ int sp[64];
    int tid = threadIdx.x;
    const int* part = blockIdx.y ? part_b : part_f;
    int* offs = blockIdx.y ? offs_b : offs_f;
    if (tid < 64) sp[tid] = (tid < nchunks) ? part[tid] : 0;
    __syncthreads();
    if (tid == 0) {                       // tiny serial exclusive scan (49 entries)
        int run = 0;
        for (int k = 0; k < 64; ++k) { int t = sp[k]; sp[k] = run; run += t; }
    }
    __syncthreads();
    int i = blockIdx.x * 256 + tid;
    if (i < n) offs[i] += sp[i >> 10];
    else if (i == n) offs[n] = sp[nchunks];
}

// ============ fill: list-driven scatter; pos-base LDS atomic gives pay slot ============
__global__ __launch_bounds__(256) void fill_kernel(const int* __restrict__ ei0,
                                                   const int* __restrict__ ei1,
                                                   const unsigned int* __restrict__ ghist,
                                                   const int* __restrict__ offs_f,
                                                   const int* __restrict__ offs_b,
                                                   const unsigned short* __restrict__ h_dsi,
                                                   const unsigned short* __restrict__ h_dti,
                                                   unsigned int* __restrict__ pay_f,
                                                   unsigned int* __restrict__ pay_b,
                                                   const unsigned short* __restrict__ list,
                                                   const unsigned int* __restrict__ cnt_bkt) {
    __shared__ unsigned int pos[FOCT_NODES]; // 25 KB: per-node NEXT global pay slot
    int bx = blockIdx.x;
    int foct = bx & 7, q = (bx >> 3) & 63, dir = bx >> 9;
    int oct = foct >> 1;                     // parent quarter
    int tid = threadIdx.x;
    const unsigned int* pref = ghist + (size_t)(dir * QCH + q) * NPACK + foct * FOCT_PACK;
    const int* offs = dir ? offs_b : offs_f;
    int lo = foct * FOCT_NODES;
    for (int d = tid; d < FOCT_NODES; d += 256) {
        unsigned int pw = pref[d >> 1];
        int cb = (d & 1) ? (int)(pw >> 16) : (int)(pw & 0xffff);
        pos[d] = (unsigned int)(offs[lo + d] + cb);
    }
    __syncthreads();
    const int* key = dir ? ei0 : ei1;
    const int* pid = dir ? ei1 : ei0;
    const unsigned short* hfac = dir ? h_dti : h_dsi;
    unsigned int* pay = dir ? pay_b : pay_f;
    const unsigned short* lst = list + ((size_t)(dir * QCH + q) * 4 + oct) * LCAP;
    int cnt = (int)cnt_bkt[dir * 256 + q * 4 + oct];
    int base = q * CHUNK;
    for (int j = tid; j < cnt; j += 256) {
        int gi = base + (int)lst[j];
        int v = key[gi];
        unsigned int d = (unsigned int)(v - lo);
        if (d < FOCT_NODES) {
            int id = pid[gi];
            unsigned int p = atomicAdd(&pos[d], 1u);
            unsigned int hb = hfac[id];
            pay[p] = (unsigned int)id | (hb << 16);
        }
    }
}

__device__ inline void acc_fma(float* acc, uint4 u, float f) {
    const __half2* h = (const __half2*)&u;
    float2 f0 = __half22float2(h[0]);
    float2 f1 = __half22float2(h[1]);
    float2 f2 = __half22float2(h[2]);
    float2 f3 = __half22float2(h[3]);
    acc[0] += f * f0.x; acc[1] += f * f0.y; acc[2] += f * f1.x; acc[3] += f * f1.y;
    acc[4] += f * f2.x; acc[5] += f * f2.y; acc[6] += f * f3.x; acc[7] += f * f3.y;
}

// ======= conv1-aggregate + relu + conv2 via MFMA epilogue; s/t via blockIdx.y =======
// r12 lesson: 8-deep gather unroll raised VGPR 36->44, occupancy 63->48%, dur +3.5us.
// Reverted to the 4-deep loop (TLP > ILP here); wave-level parallelism supplies MLP.
__global__ __launch_bounds__(256) void pull_lin2_kernel(const __half* __restrict__ As,
                                                        const __half* __restrict__ At,
                                                        __half* __restrict__ Cs,
                                                        __half* __restrict__ Ct,
                                                        const int* __restrict__ offs_f,
                                                        const int* __restrict__ offs_b,
                                                        const unsigned int* __restrict__ pay_f,
                                                        const unsigned int* __restrict__ pay_b,
                                                        const float* __restrict__ dsi,
                                                        const float* __restrict__ dti,
                                                        const float* __restrict__ sb2a,
                                                        const float* __restrict__ sb2b,
                                                        const float* __restrict__ tb2a,
                                                        const float* __restrict__ tb2b,
                                                        const __half* __restrict__ hw2, int n) {
    int y = blockIdx.y;
    const __half* xw = y ? At : As;
    __half* C = y ? Ct : Cs;
    const int* offs = y ? offs_b : offs_f;
    const unsigned int* pay = y ? pay_b : pay_f;
    const float* fac_self  = y ? dsi : dti;   // fwd: dti, bwd: dsi
    const float* fac_other = y ? dti : dsi;   // self-loop gather factor
    const float* b2a = y ? tb2a : sb2a;
    const float* b2b = y ? tb2b : sb2b;

    __shared__ __half xsh[16 * 136];          // 4.25 KB; row pad -> 2-way-free banks

    int tid = threadIdx.x;
    int ln = tid >> 4;     // node slot 0..15
    int f4 = tid & 15;     // uint4 column (8 halves)
    int v = blockIdx.x * 16 + ln;
    int i = offs[v], end = offs[v + 1];
    const uint4* xw16 = (const uint4*)xw;           // row stride = 16 uint4

    float acc[8] = {0, 0, 0, 0, 0, 0, 0, 0};
    acc_fma(acc, xw16[v * 16 + f4], fac_other[v]);  // self-loop
    while (i < end && (i & 3)) {                    // align to 16B pay boundary
        unsigned int pk = pay[i];
        acc_fma(acc, xw16[(pk & 0xffff) * 16 + f4], fac_from(pk));
        ++i;
    }
    for (; i + 3 < end; i += 4) {                   // 1 uint4 pay load + 4 gathers
        uint4 pk = *(const uint4*)(pay + i);
        int s0 = pk.x & 0xffff, s1 = pk.y & 0xffff;
        int s2 = pk.z & 0xffff, s3 = pk.w & 0xffff;
        uint4 ua = xw16[s0 * 16 + f4];
        uint4 ub = xw16[s1 * 16 + f4];
        uint4 uc = xw16[s2 * 16 + f4];
        uint4 ud = xw16[s3 * 16 + f4];
        acc_fma(acc, ua, fac_from(pk.x));
        acc_fma(acc, ub, fac_from(pk.y));
        acc_fma(acc, uc, fac_from(pk.z));
        acc_fma(acc, ud, fac_from(pk.w));
    }
    for (; i < end; ++i) {
        unsigned int pk = pay[i];
        acc_fma(acc, xw16[(pk & 0xffff) * 16 + f4], fac_from(pk));
    }

    float fs = fac_self[v];
    half8 hx;
#pragma unroll
    for (int j = 0; j < 8; ++j) hx[j] = (_Float16)fmaxf(acc[j] * fs, 0.0f);
    *(half8*)&xsh[ln * 136 + f4 * 8] = hx;
    __syncthreads();

    // ---- MFMA epilogue: wave w -> set s = w>>1 (a:mu / b:logstd), n-tile nt = w&1 ----
    int w = tid >> 6, lane = tid & 63;
    int s = w >> 1, nt = w & 1;
    int quad = lane >> 4, col = lane & 15;
    float bb = (s ? b2b : b2a)[nt * 16 + col];
    f32x4 cacc = { bb, bb, bb, bb };
    const __half* hw = hw2 + (size_t)(y * 2 + s) * 2048;   // [32][64] fp16 row-major
#pragma unroll
    for (int t = 0; t < 2; ++t) {
        half8 af = *(const half8*)&xsh[col * 136 + s * 64 + t * 32 + quad * 8];
        half8 bf = *(const half8*)&hw[(nt * 16 + col) * 64 + t * 32 + quad * 8];
        cacc = __builtin_amdgcn_mfma_f32_16x16x32_f16(af, bf, cacc, 0, 0, 0);
    }
    // D: row m = quad*4 + r (node), col n = lane&15; C stored UNSCALED fp16
    int vbase = blockIdx.x * 16 + quad * 4;
    int o = s * 32 + nt * 16 + col;
#pragma unroll
    for (int r = 0; r < 4; ++r)
        C[(size_t)(vbase + r) * 64 + o] = __float2half(cacc[r]);
}

// ================= final pull + reparametrize; s/t via blockIdx.y =================
__global__ __launch_bounds__(256) void final_pull2_kernel(const __half* __restrict__ Cs,
                                                          const __half* __restrict__ Ct,
                                                          float* __restrict__ out_s,
                                                          float* __restrict__ out_t,
                                                          const int* __restrict__ offs_f,
                                                          const int* __restrict__ offs_b,
                                                          const unsigned int* __restrict__ pay_f,
                                                          const unsigned int* __restrict__ pay_b,
                                                          const float* __restrict__ dsi,
                                                          const float* __restrict__ dti,
                                                          const float* __restrict__ noise_s,
                                                          const float* __restrict__ noise_t,
                                                          int n) {
    int y = blockIdx.y;
    const __half* xw = y ? Ct : Cs;
    float* out = y ? out_t : out_s;
    const int* offs = y ? offs_f : offs_b;                  // flipped vs conv1
    const unsigned int* pay = y ? pay_f : pay_b;
    const float* fac_self  = y ? dti : dsi;
    const float* fac_other = y ? dsi : dti;                 // self-loop gather factor
    const float* noise = y ? noise_t : noise_s;

    const uint4* xw16 = (const uint4*)xw;           // row stride = 8 uint4 (64 halves)
    int ln = threadIdx.x >> 3;
    int f4 = threadIdx.x & 7;
    int v = blockIdx.x * 32 + ln;
    if (v >= n) return;
    int i = offs[v], end = offs[v + 1];

    float acc[8] = {0, 0, 0, 0, 0, 0, 0, 0};
    acc_fma(acc, xw16[v * 8 + f4], fac_other[v]);
    while (i < end && (i & 3)) {
        unsigned int pk = pay[i];
        acc_fma(acc, xw16[(pk & 0xffff) * 8 + f4], fac_from(pk));
        ++i;
    }
    for (; i + 3 < end; i += 4) {
        uint4 pk = *(const uint4*)(pay + i);
        int s0 = pk.x & 0xffff, s1 = pk.y & 0xffff;
        int s2 = pk.z & 0xffff, s3 = pk.w & 0xffff;
        uint4 ua = xw16[s0 * 8 + f4];
        uint4 ub = xw16[s1 * 8 + f4];
        uint4 uc = xw16[s2 * 8 + f4];
        uint4 ud = xw16[s3 * 8 + f4];
        acc_fma(acc, ua, fac_from(pk.x));
        acc_fma(acc, ub, fac_from(pk.y));
        acc_fma(acc, uc, fac_from(pk.z));
        acc_fma(acc, ud, fac_from(pk.w));
    }
    for (; i < end; ++i) {
        unsigned int pk = pay[i];
        acc_fma(acc, xw16[(pk & 0xffff) * 8 + f4], fac_from(pk));
    }

    float fs = fac_self[v];
#pragma unroll
    for (int j = 0; j < 8; ++j) acc[j] *= fs;

    // lanes f4 0..3 hold mu cols; partner lane f4+4 holds logstd cols
    int lane = threadIdx.x & 63;
    float lg[8];
#pragma unroll
    for (int j = 0; j < 8; ++j) lg[j] = __shfl(acc[j], lane + 4);
    if (f4 < 4) {
        const float4* nz4 = (const float4*)noise;
        float4 n0 = nz4[v * 8 + f4 * 2];
        float4 n1 = nz4[v * 8 + f4 * 2 + 1];
        float4 r0, r1;
        r0.x = acc[0] + n0.x * expf(lg[0]) * 0.2f;
        r0.y = acc[1] + n0.y * expf(lg[1]) * 0.2f;
        r0.z = acc[2] + n0.z * expf(lg[2]) * 0.2f;
        r0.w = acc[3] + n0.w * expf(lg[3]) * 0.2f;
        r1.x = acc[4] + n1.x * expf(lg[4]) * 0.2f;
        r1.y = acc[5] + n1.y * expf(lg[5]) * 0.2f;
        r1.z = acc[6] + n1.z * expf(lg[6]) * 0.2f;
        r1.w = acc[7] + n1.w * expf(lg[7]) * 0.2f;
        float4* o4 = (float4*)out;
        o4[v * 8 + f4 * 2]     = r0;
        o4[v * 8 + f4 * 2 + 1] = r1;
    }
}

// ================= driver =================
extern "C" void kernel_launch(void* const* d_in, const int* in_sizes, int n_in,
                              void* d_out, int out_size, void* d_ws, size_t ws_size,
                              hipStream_t stream) {
    const float* s       = (const float*)d_in[0];
    const float* t       = (const float*)d_in[1];
    const int*   ei      = (const int*)d_in[2];
    const float* noise_s = (const float*)d_in[3];
    const float* noise_t = (const float*)d_in[4];
    const float* sm1_W = (const float*)d_in[5];  const float* sm1_b = (const float*)d_in[6];
    const float* sm2_W = (const float*)d_in[7];  const float* sm2_b = (const float*)d_in[8];
    const float* sl1_W = (const float*)d_in[9];  const float* sl1_b = (const float*)d_in[10];
    const float* sl2_W = (const float*)d_in[11]; const float* sl2_b = (const float*)d_in[12];
    const float* tm1_W = (const float*)d_in[13]; const float* tm1_b = (const float*)d_in[14];
    const float* tm2_W = (const float*)d_in[15]; const float* tm2_b = (const float*)d_in[16];
    const float* tl1_W = (const float*)d_in[17]; const float* tl1_b = (const float*)d_in[18];
    const float* tl2_W = (const float*)d_in[19]; const float* tl2_b = (const float*)d_in[20];

    const int* ei0 = ei;            // sources
    const int* ei1 = ei + E_EDGES;  // targets

    __half* A_s = (__half*)d_ws;                       // [N][128] unscaled fp16
    __half* A_t = A_s + (size_t)N_NODES * 128;         // [N][128]
    __half* C_s = A_t + (size_t)N_NODES * 128;         // [N][64] unscaled fp16
    __half* C_t = C_s + (size_t)N_NODES * 64;          // [N][64]
    unsigned int* pay_fwd = (unsigned int*)(C_t + (size_t)N_NODES * 64);  // E (16B-aligned)
    unsigned int* pay_bwd = pay_fwd + E_EDGES;                            // E
    float* dsi = (float*)(pay_bwd + E_EDGES);          // N
    float* dti = dsi + N_NODES;                        // N
    int* offs_fwd = (int*)(dti + N_NODES);             // N+1
    int* offs_bwd = offs_fwd + N_NODES + 1;            // N+1
    int* part_fwd = offs_bwd + N_NODES + 1;            // NCHUNKS+1
    int* part_bwd = part_fwd + NCHUNKS + 1;            // NCHUNKS+1
    unsigned short* h_dsi = (unsigned short*)(part_bwd + NCHUNKS + 1);  // N half factors
    unsigned short* h_dti = h_dsi + N_NODES;           // N half factors
    unsigned short* list  = h_dti + N_NODES;           // [512][LCAP] u16 = 4 MB
    unsigned int* cnt_bkt = (unsigned int*)(list + (size_t)HIST_BLOCKS * LCAP);  // 512 u32
    __half* hw2 = (__half*)(((uintptr_t)(cnt_bkt + 512) + 15) & ~(uintptr_t)15);  // [4][2048] fp16
    __half* hw1 = hw2 + 4 * 2048;                      // [4][8192] fp16 (lin1 weights)
    // total ~50 MB

    // ghist ALIASES the C region (both exactly 12.8 MB):
    // ghist live hist->fill; C written by pull_lin2 (after fill), read by final_pull2.
    unsigned int* ghist = (unsigned int*)C_s;          // [2][QCH][NPACK]

    float* s_out = (float*)d_out;
    float* t_out = (float*)d_out + N_NODES * 32;

    dim3 blk(256);
    dim3 agrid((N_NODES + 1 + 255) / 256, 2);
    dim3 pgrid(N_NODES / 16, 2);           // 3125 x 2
    dim3 fgrid((N_NODES + 31) / 32, 2);    // 1563 x 2

    // ---- fp16 weights for lin2 AND lin1 (one tiny launch; runs before hist_lin1) ----
    w2h_kernel<<<160, blk, 0, stream>>>(sm2_W, sl2_W, tm2_W, tl2_W,
                                        sm1_W, sl1_W, tm1_W, tl1_W, hw2, hw1);
    // ---- hist (+edge lists) fused with conv1 dual-linear (overlap) ----
    hist_lin1_kernel<<<HL_GRID, blk, 0, stream>>>(
        ei0, ei1, ghist, list, cnt_bkt,
        s, t, hw1, sm1_b, sl1_b, tm1_b, tl1_b,
        A_s, A_t, N_NODES);
    // ---- fused nodescan + block scan + degree factors ----
    scan_fused_kernel<<<dim3(NCHUNKS, 2), 1024, 0, stream>>>(
        ghist, offs_fwd, offs_bwd, part_fwd, part_bwd,
        dsi, dti, h_dsi, h_dti, N_NODES);
    addback_kernel<<<agrid, blk, 0, stream>>>(offs_fwd, offs_bwd, part_fwd, part_bwd,
                                              N_NODES, NCHUNKS);
    // ---- list-driven fill (half-quarter blocks; pos-base LDS atomics) ----
    fill_kernel<<<FILL_BLOCKS, blk, 0, stream>>>(ei0, ei1, ghist, offs_fwd, offs_bwd,
                                                 h_dsi, h_dti, pay_fwd, pay_bwd,
                                                 list, cnt_bkt);

    // ---- pulls (packed-factor gathers; MFMA lin2 epilogue) ----
    pull_lin2_kernel<<<pgrid, blk, 0, stream>>>(A_s, A_t, C_s, C_t,
                                                offs_fwd, offs_bwd, pay_fwd, pay_bwd,
                                                dsi, dti,
                                                sm2_b, sl2_b, tm2_b, tl2_b, hw2, N_NODES);
    final_pull2_kernel<<<fgrid, blk, 0, stream>>>(C_s, C_t, s_out, t_out,
                                                  offs_fwd, offs_bwd, pay_fwd, pay_bwd,
                                                  dsi, dti, noise_s, noise_t, N_NODES);
}